// Round 5
// baseline (2840.498 us; speedup 1.0000x reference)
//
#include <hip/hip_runtime.h>
#include <math.h>

#define TILE 128
#define BK 64

typedef __bf16 bf16x8 __attribute__((ext_vector_type(8)));
typedef float f32x4 __attribute__((ext_vector_type(4)));
typedef short short8 __attribute__((ext_vector_type(8)));
typedef unsigned int uint4v __attribute__((ext_vector_type(4)));

__device__ __forceinline__ float bf2f(unsigned short u) {
  union { unsigned int i; float f; } v; v.i = ((unsigned int)u) << 16; return v.f;
}
__device__ __forceinline__ unsigned short f2bf(float f) {
  union { float fl; unsigned int i; } v; v.fl = f;
  unsigned int x = v.i;
  return (unsigned short)((x + 0x7FFFu + ((x >> 16) & 1u)) >> 16);  // RNE
}
__device__ __forceinline__ unsigned int cvt_pk_bf16(float lo, float hi) {
  unsigned int r;
  asm("v_cvt_pk_bf16_f32 %0, %1, %2" : "=v"(r) : "v"(lo), "v"(hi));
  return r;
}
// async global->LDS, 16B per lane. lds ptr wave-uniform (HW adds lane*16).
__device__ __forceinline__ void gl_lds16(const unsigned short* g, void* l) {
  __builtin_amdgcn_global_load_lds(
      (const __attribute__((address_space(1))) unsigned int*)g,
      (__attribute__((address_space(3))) unsigned int*)l, 16, 0, 0);
}

// ============================================================================
// 256x256 bf16 GEMM, 16x16x32 MFMA (conflict-free swizzle), 4 phases/K-tile
// with REGISTER PREFETCH PIPELINE: each phase issues next quadrant's ds_reads,
// MFMAs on regs loaded last phase (counted lgkmcnt). A-frags dbuf af[2];
// B-frags dbuf across tiles (bfE/bfO, paired-tile loop => static indexing).
// global_load_lds staging w/ pre-swizzled source (XOR ((row&7)<<4)),
// counted vmcnt, XCD-chunked + 4x4 super-tiled block mapping.
// ============================================================================
template<int CF32, int HAS_BIAS>
__global__ __launch_bounds__(512)
void gemm256(const unsigned short* __restrict__ A,
             const unsigned short* __restrict__ B,
             const float* __restrict__ bias,
             void* __restrict__ Cv,
             int K, int lda, int ldb, int ldc, int nbn)
{
  __shared__ alignas(16) unsigned char LDS[131072];
  const int NT = K >> 6;   // even (K % 128 == 0)

  // XCD chunk (gridDim%8==0) then 4x4 super-tile (nbm%4==0, nbn%4==0)
  const int nwg = (int)gridDim.x;
  const int bid = (int)blockIdx.x;
  const int s = (bid & 7) * (nwg >> 3) + (bid >> 3);
  const int sTile = s >> 4, w = s & 15;
  const int snb = nbn >> 2;
  const int tm = ((sTile / snb) * 4 + (w >> 2)) * 256;
  const int tn = ((sTile % snb) * 4 + (w & 3)) * 256;

  const int tid = (int)threadIdx.x;
  const int lane = tid & 63;
  const int wv = tid >> 6;      // 0..7
  const int wm = wv >> 2;       // 0..1 (A half)
  const int wn = wv & 3;        // 0..3
  const int l16 = lane & 15;
  const int kg = lane >> 4;

  // staging: linear LDS dest; content[o] = logical[o ^ ((row&7)<<4)], row=o>>7
  const int srow = tid >> 3;
  const int scolb = ((tid & 7) * 16) ^ (((tid >> 3) & 7) << 4);
  const unsigned short* Abase = A + (long)tm * lda + (scolb >> 1);
  const unsigned short* Bbase = B + (long)tn * ldb + (scolb >> 1);
  const int ldsw = wv * 1024;

  // frag read cols (full-XOR swizzle on byte col, row&7 == l16&7)
  const int colswz0 = (kg * 16) ^ ((l16 & 7) << 4);
  const int colswz1 = (64 + kg * 16) ^ ((l16 & 7) << 4);
  const int bq16 = (wn >> 1) * 16384;
  const int brow = (wn & 1) * 64;

  f32x4 acc[8][4];
  #pragma unroll
  for (int i = 0; i < 8; ++i)
    #pragma unroll
    for (int j = 0; j < 4; ++j)
      #pragma unroll
      for (int e = 0; e < 4; ++e) acc[i][j][e] = 0.f;

  auto stageA = [&](int t, int buf) {
    #pragma unroll
    for (int h = 0; h < 2; ++h)
      #pragma unroll
      for (int i = 0; i < 2; ++i)
        gl_lds16(Abase + (long)(h * 128 + srow + i * 64) * lda + t * 64,
                 &LDS[buf * 32768 + h * 16384 + i * 8192 + ldsw]);
  };
  auto stageBh = [&](int t, int h, int buf) {
    #pragma unroll
    for (int i = 0; i < 2; ++i)
      gl_lds16(Bbase + (long)(h * 128 + srow + i * 64) * ldb + t * 64,
               &LDS[65536 + buf * 32768 + h * 16384 + i * 8192 + ldsw]);
  };

  // prologue: tiles 0,1 staged (8 loads each); wait tile 0 only
  stageA(0, 0); stageBh(0, 0, 0); stageBh(0, 1, 0);
  stageA(1, 1); stageBh(1, 0, 1); stageBh(1, 1, 1);
  asm volatile("s_waitcnt vmcnt(8)" ::: "memory");
  __builtin_amdgcn_s_barrier();

  bf16x8 af[2][2][2];          // [parity][row-in-pair][k-half]
  bf16x8 bfE[4][2], bfO[4][2]; // B frags, tile-parity double buffer

#define LOADA(P, RB, BASE)                                                     \
  af[P][0][0] = *(const bf16x8*)((BASE) + ((RB) * 16 + l16) * 128 + colswz0);  \
  af[P][0][1] = *(const bf16x8*)((BASE) + ((RB) * 16 + l16) * 128 + colswz1);  \
  af[P][1][0] = *(const bf16x8*)((BASE) + ((RB + 1) * 16 + l16) * 128 + colswz0); \
  af[P][1][1] = *(const bf16x8*)((BASE) + ((RB + 1) * 16 + l16) * 128 + colswz1);

#define LOADB(BF, BASE)                                                        \
  _Pragma("unroll")                                                            \
  for (int ni = 0; ni < 4; ++ni) {                                             \
    BF[ni][0] = *(const bf16x8*)((BASE) + (brow + ni * 16 + l16) * 128 + colswz0); \
    BF[ni][1] = *(const bf16x8*)((BASE) + (brow + ni * 16 + l16) * 128 + colswz1); \
  }

#define MFMA16(R0, P, BF)                                                      \
  _Pragma("unroll")                                                            \
  for (int ni = 0; ni < 4; ++ni) {                                             \
    acc[R0][ni] = __builtin_amdgcn_mfma_f32_16x16x32_bf16(af[P][0][0], BF[ni][0], acc[R0][ni], 0, 0, 0);         \
    acc[R0][ni] = __builtin_amdgcn_mfma_f32_16x16x32_bf16(af[P][0][1], BF[ni][1], acc[R0][ni], 0, 0, 0);         \
    acc[R0 + 1][ni] = __builtin_amdgcn_mfma_f32_16x16x32_bf16(af[P][1][0], BF[ni][0], acc[R0 + 1][ni], 0, 0, 0); \
    acc[R0 + 1][ni] = __builtin_amdgcn_mfma_f32_16x16x32_bf16(af[P][1][1], BF[ni][1], acc[R0 + 1][ni], 0, 0, 0); \
  }

// phase: issue next quadrant's reads (+optional stage), wait oldest (counted),
// MFMA on regs loaded last phase, barrier.
#define PHASE_STD(P_LOAD, RB_LOAD, R0, P_USE, BF, EXTRA)                       \
  LOADA(P_LOAD, RB_LOAD, aB)                                                   \
  EXTRA                                                                        \
  asm volatile("s_waitcnt lgkmcnt(4)" ::: "memory");                           \
  __builtin_amdgcn_sched_barrier(0);                                           \
  __builtin_amdgcn_s_setprio(1);                                               \
  MFMA16(R0, P_USE, BF)                                                        \
  __builtin_amdgcn_s_setprio(0);                                               \
  __builtin_amdgcn_s_barrier();

// Safety ledger (FIFO per-wave in-order DS completion):
//  ph0 lgkmcnt(4): drains B(t)+A0 (12 preloaded) -> MFMA rows0-1 OK
//  stageA(t+1)@ph1 writes opposite A-buf; all waves past ph0-end barrier have
//    drained tile t-1's last A reads (its ph3 lgkm) -> safe
//  stageB(t+2)@ph2 writes B(t)'s slot; all waves past ph1-end barrier have
//    drained B(t) reads (ph0 lgkm) -> safe
//  ph3: per-wave vmcnt THEN barrier => ALL waves' DMA for tile t+1 complete
//    before ANY wave reads B(t+1)/A0(t+1); lgkmcnt(12) drains af[1]rows6-7
#define TILE_BODY(TPAR, BFU, BFN)                                              \
  {                                                                            \
    const unsigned char* aB  = &LDS[(TPAR) * 32768 + wm * 16384];              \
    const unsigned char* naB = &LDS[(1 - (TPAR)) * 32768 + wm * 16384];        \
    const unsigned char* nbB = &LDS[65536 + (1 - (TPAR)) * 32768 + bq16];      \
    PHASE_STD(1, 2, 0, 0, BFU, )                                               \
    PHASE_STD(0, 4, 2, 1, BFU,                                                 \
              if (t > 0 && t + 1 < NT) stageA(t + 1, 1 - (TPAR));)             \
    PHASE_STD(1, 6, 4, 0, BFU,                                                 \
              if (t + 2 < NT) { stageBh(t + 2, 0, TPAR); stageBh(t + 2, 1, TPAR); }) \
    if (t + 1 < NT) {                                                          \
      if (t >= NT - 2) { asm volatile("s_waitcnt vmcnt(0)" ::: "memory"); }    \
      else             { asm volatile("s_waitcnt vmcnt(4)" ::: "memory"); }    \
      __builtin_amdgcn_s_barrier();                                            \
      LOADB(BFN, nbB)                                                          \
      LOADA(0, 0, naB)                                                         \
      asm volatile("s_waitcnt lgkmcnt(12)" ::: "memory");                      \
    } else {                                                                   \
      asm volatile("s_waitcnt lgkmcnt(0)" ::: "memory");                       \
    }                                                                          \
    __builtin_amdgcn_sched_barrier(0);                                         \
    __builtin_amdgcn_s_setprio(1);                                             \
    MFMA16(6, 1, BFU)                                                          \
    __builtin_amdgcn_s_setprio(0);                                             \
  }

  // preload tile 0: B frags (8 reads) + A rows 0-1 (4 reads); ph0 lgkm waits
  {
    const unsigned char* aB = &LDS[wm * 16384];
    const unsigned char* bB = &LDS[65536 + bq16];
    LOADB(bfE, bB)
    LOADA(0, 0, aB)
  }

  for (int t2 = 0; t2 < NT; t2 += 2) {
    { const int t = t2;     TILE_BODY(0, bfE, bfO) }
    { const int t = t2 + 1; TILE_BODY(1, bfO, bfE) }
  }
#undef LOADA
#undef LOADB
#undef MFMA16
#undef PHASE_STD
#undef TILE_BODY

  // epilogue: C/D layout col=lane&15, row=(lane>>4)*4 + j (m89-verified)
  #pragma unroll
  for (int ni = 0; ni < 4; ++ni) {
    const int col = tn + wn * 64 + ni * 16 + l16;
    const float bv = HAS_BIAS ? bias[col] : 0.f;
    #pragma unroll
    for (int mi = 0; mi < 8; ++mi) {
      #pragma unroll
      for (int jj = 0; jj < 4; ++jj) {
        const int row = tm + wm * 128 + mi * 16 + kg * 4 + jj;
        const float v = acc[mi][ni][jj] + bv;
        if (CF32) ((float*)Cv)[(long)row * ldc + col] = v;
        else ((unsigned short*)Cv)[(long)row * ldc + col] = f2bf(v);
      }
    }
  }
}

// ============================================================================
// f32 -> bf16 convert (vectorized, grid-stride), n8 = n/8
// ============================================================================
__global__ __launch_bounds__(256)
void cvt_bf16(const float* __restrict__ in, unsigned short* __restrict__ out, long n8)
{
  long i = (long)blockIdx.x * 256 + threadIdx.x;
  const long stride = (long)gridDim.x * 256;
  for (; i < n8; i += stride) {
    f32x4 v0 = *(const f32x4*)(in + i * 8);
    f32x4 v1 = *(const f32x4*)(in + i * 8 + 4);
    uint4v o;
    o[0] = cvt_pk_bf16(v0[0], v0[1]);
    o[1] = cvt_pk_bf16(v0[2], v0[3]);
    o[2] = cvt_pk_bf16(v1[0], v1[1]);
    o[3] = cvt_pk_bf16(v1[2], v1[3]);
    *(uint4v*)(out + i * 8) = o;
  }
}

// ============================================================================
// 128x128 bf16 GEMM (R2-proven) for small batched stages
// ============================================================================
template<int HAS_BIAS>
__global__ __launch_bounds__(256, 2)
void gemm_bt(const unsigned short* __restrict__ A, const unsigned short* __restrict__ B,
             const float* __restrict__ bias, unsigned short* __restrict__ C,
             int M, int N, int K, int lda, int ldb, int ldc,
             long sAo, long sAi, int nAi,
             long sBo, long sBi, int nBi,
             long sCo, long sCi, int nCi,
             float alpha)
{
  __shared__ alignas(16) unsigned short lA[TILE * BK];
  __shared__ alignas(16) unsigned short lB[TILE * BK];

  const int z = blockIdx.z;
  const unsigned short* Ab = A + (long)(z / nAi) * sAo + (long)(z % nAi) * sAi;
  const unsigned short* Bb = B + (long)(z / nBi) * sBo + (long)(z % nBi) * sBi;
  unsigned short* Cb = C + (long)(z / nCi) * sCo + (long)(z % nCi) * sCi;

  const int tm = blockIdx.y * TILE;
  const int tn = blockIdx.x * TILE;
  const int tid = (int)threadIdx.x;
  const int lane = tid & 63;
  const int wave = tid >> 6;
  const int wm = (wave >> 1) * 64;
  const int wn = (wave & 1) * 64;
  const int l16 = lane & 15;
  const int kg = lane >> 4;

  f32x4 acc[4][4];
  #pragma unroll
  for (int i = 0; i < 4; ++i)
    #pragma unroll
    for (int j = 0; j < 4; ++j)
      #pragma unroll
      for (int e = 0; e < 4; ++e) acc[i][j][e] = 0.f;

  const int srow = tid >> 3;
  const int sc8 = (tid & 7) * 8;
  const int fbA = (wm + l16) * BK + kg * 8;
  const int fbB = (wn + l16) * BK + kg * 8;

  for (int k0 = 0; k0 < K; k0 += BK) {
    short8 ra[4], rb[4];
    #pragma unroll
    for (int i = 0; i < 4; ++i) {
      ra[i] = *(const short8*)(Ab + (long)(tm + srow + i * 32) * lda + k0 + sc8);
      rb[i] = *(const short8*)(Bb + (long)(tn + srow + i * 32) * ldb + k0 + sc8);
    }
    __syncthreads();
    #pragma unroll
    for (int i = 0; i < 4; ++i) {
      *(short8*)&lA[(srow + i * 32) * BK + sc8] = ra[i];
      *(short8*)&lB[(srow + i * 32) * BK + sc8] = rb[i];
    }
    __syncthreads();
    #pragma unroll
    for (int kk = 0; kk < 2; ++kk) {
      bf16x8 af[4], bfr[4];
      #pragma unroll
      for (int mi = 0; mi < 4; ++mi)
        af[mi] = *(const bf16x8*)&lA[fbA + mi * 16 * BK + kk * 32];
      #pragma unroll
      for (int ni = 0; ni < 4; ++ni)
        bfr[ni] = *(const bf16x8*)&lB[fbB + ni * 16 * BK + kk * 32];
      #pragma unroll
      for (int mi = 0; mi < 4; ++mi)
        #pragma unroll
        for (int ni = 0; ni < 4; ++ni)
          acc[mi][ni] = __builtin_amdgcn_mfma_f32_16x16x32_bf16(af[mi], bfr[ni], acc[mi][ni], 0, 0, 0);
    }
  }

  #pragma unroll
  for (int ni = 0; ni < 4; ++ni) {
    int col = tn + wn + ni * 16 + l16;
    float bv = HAS_BIAS ? bias[col] : 0.f;
    #pragma unroll
    for (int mi = 0; mi < 4; ++mi)
      #pragma unroll
      for (int j = 0; j < 4; ++j) {
        int row = tm + wm + mi * 16 + kg * 4 + j;
        Cb[(long)row * ldc + col] = f2bf(acc[mi][ni][j] * alpha + bv);
      }
  }
}

// In-place LayerNorm over rows of 512 bf16. One wave/row. g,b f32.
__global__ __launch_bounds__(256)
void ln_rows(unsigned short* __restrict__ t, const float* __restrict__ g,
             const float* __restrict__ b)
{
  const int row = blockIdx.x * 4 + ((int)threadIdx.x >> 6);
  const int lane = (int)threadIdx.x & 63;
  unsigned short* p = t + (long)row * 512 + lane * 8;
  short8 rv = *(const short8*)p;
  float x[8];
  #pragma unroll
  for (int j = 0; j < 8; ++j) x[j] = bf2f((unsigned short)rv[j]);
  float s = 0.f;
  #pragma unroll
  for (int j = 0; j < 8; ++j) s += x[j];
  #pragma unroll
  for (int off = 32; off > 0; off >>= 1) s += __shfl_xor(s, off, 64);
  float mu = s * (1.f / 512.f);
  float vs = 0.f;
  #pragma unroll
  for (int j = 0; j < 8; ++j) { float d = x[j] - mu; vs += d * d; }
  #pragma unroll
  for (int off = 32; off > 0; off >>= 1) vs += __shfl_xor(vs, off, 64);
  float rs = rsqrtf(vs * (1.f / 512.f) + 1e-5f);
  f32x4 gv0 = *(const f32x4*)(g + lane * 8);
  f32x4 gv1 = *(const f32x4*)(g + lane * 8 + 4);
  f32x4 bv0 = *(const f32x4*)(b + lane * 8);
  f32x4 bv1 = *(const f32x4*)(b + lane * 8 + 4);
  short8 ov;
  #pragma unroll
  for (int j = 0; j < 4; ++j) ov[j] = (short)f2bf((x[j] - mu) * rs * gv0[j] + bv0[j]);
  #pragma unroll
  for (int j = 0; j < 4; ++j) ov[4 + j] = (short)f2bf((x[4 + j] - mu) * rs * gv1[j] + bv1[j]);
  *(short8*)p = ov;
}

// w = (val * gelu_exact(gate)) / max(||.||2, 1e-12)
__global__ __launch_bounds__(256)
void gate_norm(const unsigned short* __restrict__ h, unsigned short* __restrict__ w)
{
  const int row = blockIdx.x * 4 + ((int)threadIdx.x >> 6);
  const int lane = (int)threadIdx.x & 63;
  const unsigned short* hp = h + (long)row * 1024 + lane * 8;
  short8 vv = *(const short8*)hp;
  short8 gg = *(const short8*)(hp + 512);
  float wv[8];
  float ssq = 0.f;
  #pragma unroll
  for (int j = 0; j < 8; ++j) {
    float val = bf2f((unsigned short)vv[j]);
    float gt  = bf2f((unsigned short)gg[j]);
    float tt  = val * (0.5f * gt * (1.f + erff(gt * 0.70710678118654752f)));
    wv[j] = tt;
    ssq += tt * tt;
  }
  #pragma unroll
  for (int off = 32; off > 0; off >>= 1) ssq += __shfl_xor(ssq, off, 64);
  float scale = 1.f / fmaxf(sqrtf(ssq), 1e-12f);
  short8 ov;
  #pragma unroll
  for (int j = 0; j < 8; ++j) ov[j] = (short)f2bf(wv[j] * scale);
  *(short8*)(w + (long)row * 512 + lane * 8) = ov;
}

// v (B,S,E) bf16 -> vT (B*H, 512d, 512t)
__global__ __launch_bounds__(256)
void transpose_v(const unsigned short* __restrict__ v, unsigned short* __restrict__ vT)
{
  __shared__ alignas(16) unsigned short lt[64][72];
  const int bh = blockIdx.z;
  const int b = bh >> 3, hh = bh & 7;
  const int d0 = blockIdx.x * 64, t0 = blockIdx.y * 64;
  const int tid = (int)threadIdx.x;
  const unsigned short* src = v + (long)b * (512L * 4096L) + hh * 512;
  #pragma unroll
  for (int it = 0; it < 2; ++it) {
    int ci = it * 256 + tid;
    int r = ci >> 3, c8 = (ci & 7) * 8;
    *(short8*)&lt[r][c8] = *(const short8*)(src + (long)(t0 + r) * 4096 + d0 + c8);
  }
  __syncthreads();
  unsigned short* dst = vT + ((long)bh * 512 + d0) * 512 + t0;
  #pragma unroll
  for (int it = 0; it < 2; ++it) {
    int ci = it * 256 + tid;
    int rr = ci >> 3, c8 = (ci & 7) * 8;
    short8 o;
    #pragma unroll
    for (int j = 0; j < 8; ++j) o[j] = (short)lt[c8 + j][rr];
    *(short8*)(dst + (long)rr * 512 + c8) = o;
  }
}

extern "C" void kernel_launch(void* const* d_in, const int* in_sizes, int n_in,
                              void* d_out, int out_size, void* d_ws, size_t ws_size,
                              hipStream_t stream)
{
  (void)in_sizes; (void)n_in; (void)out_size; (void)ws_size;
  const float* x   = (const float*)d_in[0];
  const float* Wq  = (const float*)d_in[1];
  const float* bq  = (const float*)d_in[2];
  const float* Wk  = (const float*)d_in[3];
  const float* bk  = (const float*)d_in[4];
  const float* Wv  = (const float*)d_in[5];
  const float* bv  = (const float*)d_in[6];
  const float* g_q = (const float*)d_in[7];
  const float* b_q = (const float*)d_in[8];
  const float* g_k = (const float*)d_in[9];
  const float* b_k = (const float*)d_in[10];
  const float* Wg  = (const float*)d_in[11];
  const float* bg  = (const float*)d_in[12];
  const float* Wo  = (const float*)d_in[13];
  const float* bo  = (const float*)d_in[14];
  float* out = (float*)d_out;

  const long NE  = 33554432L;   // B*S*E
  const long NE2 = NE / 2;      // 4096*4096
  unsigned short* ws    = (unsigned short*)d_ws;
  unsigned short* xb    = ws;
  unsigned short* Wslot = ws + NE;
  unsigned short* qbuf  = ws + NE + NE2;
  unsigned short* kbuf  = ws + 2 * NE + NE2;
  unsigned short* vbuf  = ws + 3 * NE + NE2;
  unsigned short* Wob   = ws + 4 * NE + NE2;
  unsigned short* Wgb   = ws + 5 * NE;
  unsigned short* sbuf  = xb;                 // scores (x dead after projections)
  unsigned short* vT    = qbuf;               // q dead after scores
  unsigned short* hbuf  = kbuf;               // spans kbuf+vbuf, both dead
  unsigned short* wbuf  = xb;                 // scores dead after h-GEMM
  unsigned short* obuf  = kbuf;               // h dead after gate_norm

  dim3 blk256(256), blk512(512);
  const float inv_sqrt_hd = 0.044194173824159216f;  // 1/sqrt(512)

  cvt_bf16<<<16384, blk256, 0, stream>>>(x, xb, NE / 8);
  cvt_bf16<<<256, blk256, 0, stream>>>(Wg, Wgb, 524288L / 8);
  cvt_bf16<<<8192, blk256, 0, stream>>>(Wo, Wob, NE2 / 8);

  cvt_bf16<<<8192, blk256, 0, stream>>>(Wq, Wslot, NE2 / 8);
  gemm256<0, 1><<<512, blk512, 0, stream>>>(xb, Wslot, bq, qbuf,
      4096, 4096, 4096, 4096, 16);
  cvt_bf16<<<8192, blk256, 0, stream>>>(Wk, Wslot, NE2 / 8);
  gemm256<0, 1><<<512, blk512, 0, stream>>>(xb, Wslot, bk, kbuf,
      4096, 4096, 4096, 4096, 16);
  cvt_bf16<<<8192, blk256, 0, stream>>>(Wv, Wslot, NE2 / 8);
  gemm256<0, 1><<<512, blk512, 0, stream>>>(xb, Wslot, bv, vbuf,
      4096, 4096, 4096, 4096, 16);

  ln_rows<<<16384, blk256, 0, stream>>>(qbuf, g_q, b_q);
  ln_rows<<<16384, blk256, 0, stream>>>(kbuf, g_k, b_k);

  // scores = q @ k^T / sqrt(HD), per (b,h)  -> sbuf (=xb)
  gemm_bt<0><<<dim3(4, 4, 128), blk256, 0, stream>>>(qbuf, kbuf, nullptr, sbuf,
      512, 512, 512, 4096, 4096, 512,
      2097152L, 512L, 8, 2097152L, 512L, 8, 262144L, 0L, 1, inv_sqrt_hd);

  transpose_v<<<dim3(8, 8, 128), blk256, 0, stream>>>(vbuf, vT);

  // h = scores @ Wg^T + bg -> hbuf
  gemm_bt<1><<<dim3(8, 4, 128), blk256, 0, stream>>>(sbuf, Wgb, bg, hbuf,
      512, 1024, 512, 512, 512, 1024,
      262144L, 0L, 1, 0L, 0L, 1, 524288L, 0L, 1, 1.f);

  gate_norm<<<16384, blk256, 0, stream>>>(hbuf, wbuf);

  // attn_out = w @ vT^T -> obuf, (B,S,E) layout
  gemm_bt<0><<<dim3(4, 4, 128), blk256, 0, stream>>>(wbuf, vT, nullptr, obuf,
      512, 512, 512, 512, 512, 4096,
      262144L, 0L, 1, 262144L, 0L, 1, 2097152L, 512L, 8, 1.f);

  // final = attn_out @ Wo^T + bo -> d_out (f32)
  gemm256<1, 1><<<512, blk512, 0, stream>>>(obuf, Wob, bo, out,
      4096, 4096, 4096, 4096, 16);
}

// Round 6
// 1428.445 us; speedup vs baseline: 1.9885x; 1.9885x over previous
//
#include <hip/hip_runtime.h>
#include <math.h>

typedef __bf16 bf16x8 __attribute__((ext_vector_type(8)));
typedef float f32x4 __attribute__((ext_vector_type(4)));
typedef short short8 __attribute__((ext_vector_type(8)));
typedef unsigned int uint4v __attribute__((ext_vector_type(4)));

__device__ __forceinline__ float bf2f(unsigned short u) {
  union { unsigned int i; float f; } v; v.i = ((unsigned int)u) << 16; return v.f;
}
__device__ __forceinline__ unsigned short f2bf(float f) {
  union { float fl; unsigned int i; } v; v.fl = f;
  unsigned int x = v.i;
  return (unsigned short)((x + 0x7FFFu + ((x >> 16) & 1u)) >> 16);  // RNE
}
__device__ __forceinline__ unsigned int cvt_pk_bf16(float lo, float hi) {
  unsigned int r;
  asm("v_cvt_pk_bf16_f32 %0, %1, %2" : "=v"(r) : "v"(lo), "v"(hi));
  return r;
}
// async global->LDS, 16B per lane. lds ptr wave-uniform (HW adds lane*16).
__device__ __forceinline__ void gl_lds16(const unsigned short* g, void* l) {
  __builtin_amdgcn_global_load_lds(
      (const __attribute__((address_space(1))) unsigned int*)g,
      (__attribute__((address_space(3))) unsigned int*)l, 16, 0, 0);
}

// ============================================================================
// 256x256 bf16 GEMM, 16x16x32 MFMA, R3-proven 4-phase schedule (0 bank
// conflicts, counted vmcnt). Modes:
//  BATCH=0: 1D grid, XCD-chunked + 4x4 super-tiled mapping (nbm%4==0, nbn%4==0,
//           grid%8==0). BATCH=1: blockIdx.x = tile in batch, blockIdx.z = batch
//           with (z/nXi)*sXo + (z%nXi)*sXi offsets.
//  SPLIT3: N spans 3 concatenated 4096-col weight groups; bias/output selected
//          per block by tn>>12 (block-uniform).
// ============================================================================
template<int BATCH, int SPLIT3, int CF32, int HAS_BIAS>
__global__ __launch_bounds__(512)
void gemm256(const unsigned short* __restrict__ A,
             const unsigned short* __restrict__ B,
             const float* __restrict__ b0, const float* __restrict__ b1,
             const float* __restrict__ b2,
             void* __restrict__ C0, void* __restrict__ C1, void* __restrict__ C2,
             int K, int lda, int ldb, int ldc, int nbn, float alpha,
             long sAo, long sAi, int nAi,
             long sBo, long sBi, int nBi,
             long sCo, long sCi, int nCi)
{
  __shared__ alignas(16) unsigned char LDS[131072];
  const int NT = K >> 6;   // even, >= 2

  int tm, tn;
  long offA = 0, offB = 0, offC = 0;
  if (BATCH) {
    const int bx = (int)blockIdx.x;
    tm = (bx / nbn) * 256;
    tn = (bx % nbn) * 256;
    const int z = (int)blockIdx.z;
    offA = (long)(z / nAi) * sAo + (long)(z % nAi) * sAi;
    offB = (long)(z / nBi) * sBo + (long)(z % nBi) * sBi;
    offC = (long)(z / nCi) * sCo + (long)(z % nCi) * sCi;
  } else {
    const int nwg = (int)gridDim.x;
    const int bid = (int)blockIdx.x;
    const int s = (bid & 7) * (nwg >> 3) + (bid >> 3);
    const int sTile = s >> 4, w = s & 15;
    const int snb = nbn >> 2;
    tm = ((sTile / snb) * 4 + (w >> 2)) * 256;
    tn = ((sTile % snb) * 4 + (w & 3)) * 256;
  }

  const int tid = (int)threadIdx.x;
  const int lane = tid & 63;
  const int wv = tid >> 6;      // 0..7
  const int wm = wv >> 2;       // 0..1 (A half)
  const int wn = wv & 3;        // 0..3
  const int l16 = lane & 15;
  const int kg = lane >> 4;

  // staging: linear LDS dest; content[o] = logical[o ^ ((row&7)<<4)], row=o>>7
  const int srow = tid >> 3;
  const int scolb = ((tid & 7) * 16) ^ (((tid >> 3) & 7) << 4);
  const unsigned short* Abase = A + offA + (long)tm * lda + (scolb >> 1);
  const unsigned short* Bbase = B + offB + (long)tn * ldb + (scolb >> 1);
  const int ldsw = wv * 1024;

  // frag read cols (full-XOR swizzle on byte col, row&7 == l16&7)
  const int colswz0 = (kg * 16) ^ ((l16 & 7) << 4);
  const int colswz1 = (64 + kg * 16) ^ ((l16 & 7) << 4);

  f32x4 acc[8][4];
  #pragma unroll
  for (int i = 0; i < 8; ++i)
    #pragma unroll
    for (int j = 0; j < 4; ++j)
      #pragma unroll
      for (int e = 0; e < 4; ++e) acc[i][j][e] = 0.f;

  auto stageA = [&](int t) {
    const int buf = t & 1;
    #pragma unroll
    for (int h = 0; h < 2; ++h)
      #pragma unroll
      for (int i = 0; i < 2; ++i)
        gl_lds16(Abase + (long)(h * 128 + srow + i * 64) * lda + t * 64,
                 &LDS[buf * 32768 + h * 16384 + i * 8192 + ldsw]);
  };
  auto stageBh = [&](int t, int h) {
    const int buf = t & 1;
    #pragma unroll
    for (int i = 0; i < 2; ++i)
      gl_lds16(Bbase + (long)(h * 128 + srow + i * 64) * ldb + t * 64,
               &LDS[65536 + buf * 32768 + h * 16384 + i * 8192 + ldsw]);
  };

  // prologue: tiles 0,1 staged (8 loads each); wait tile 0 only
  stageA(0); stageBh(0, 0); stageBh(0, 1);
  stageA(1); stageBh(1, 0); stageBh(1, 1);
  asm volatile("s_waitcnt vmcnt(8)" ::: "memory");
  __builtin_amdgcn_s_barrier();

  for (int t = 0; t < NT; ++t) {
    const unsigned char* aB = &LDS[(t & 1) * 32768 + wm * 16384];
    const unsigned char* bB = &LDS[65536 + (t & 1) * 32768 + (wn >> 1) * 16384];
    const int brow = (wn & 1) * 64;
    bf16x8 bfrag[4][2];
    #pragma unroll
    for (int j = 0; j < 4; ++j) {
      // ds-load this quadrant's A rows
      bf16x8 a0k0 = *(const bf16x8*)(aB + ((2 * j + 0) * 16 + l16) * 128 + colswz0);
      bf16x8 a0k1 = *(const bf16x8*)(aB + ((2 * j + 0) * 16 + l16) * 128 + colswz1);
      bf16x8 a1k0 = *(const bf16x8*)(aB + ((2 * j + 1) * 16 + l16) * 128 + colswz0);
      bf16x8 a1k1 = *(const bf16x8*)(aB + ((2 * j + 1) * 16 + l16) * 128 + colswz1);
      if (j == 0) {
        #pragma unroll
        for (int ni = 0; ni < 4; ++ni) {
          bfrag[ni][0] = *(const bf16x8*)(bB + (brow + ni * 16 + l16) * 128 + colswz0);
          bfrag[ni][1] = *(const bf16x8*)(bB + (brow + ni * 16 + l16) * 128 + colswz1);
        }
        if (t > 0 && t + 1 < NT) stageA(t + 1);      // other A buf; prev readers done
      } else if (j == 1) {
        if (t + 2 < NT) stageBh(t + 2, 0);           // B(t) fully read at j==0
      } else if (j == 2) {
        if (t + 2 < NT) stageBh(t + 2, 1);
      }
      __builtin_amdgcn_s_barrier();
      asm volatile("s_waitcnt lgkmcnt(0)" ::: "memory");
      __builtin_amdgcn_sched_barrier(0);
      __builtin_amdgcn_s_setprio(1);
      #pragma unroll
      for (int ni = 0; ni < 4; ++ni) {
        acc[2 * j + 0][ni] = __builtin_amdgcn_mfma_f32_16x16x32_bf16(a0k0, bfrag[ni][0], acc[2 * j + 0][ni], 0, 0, 0);
        acc[2 * j + 0][ni] = __builtin_amdgcn_mfma_f32_16x16x32_bf16(a0k1, bfrag[ni][1], acc[2 * j + 0][ni], 0, 0, 0);
        acc[2 * j + 1][ni] = __builtin_amdgcn_mfma_f32_16x16x32_bf16(a1k0, bfrag[ni][0], acc[2 * j + 1][ni], 0, 0, 0);
        acc[2 * j + 1][ni] = __builtin_amdgcn_mfma_f32_16x16x32_bf16(a1k1, bfrag[ni][1], acc[2 * j + 1][ni], 0, 0, 0);
      }
      __builtin_amdgcn_s_setprio(0);
      if (j == 3) {
        // A(t+1),B(t+1) must land; B(t+2) (4 newest) may stay in flight
        if (t >= NT - 2) { asm volatile("s_waitcnt vmcnt(0)" ::: "memory"); }
        else             { asm volatile("s_waitcnt vmcnt(4)" ::: "memory"); }
        __builtin_amdgcn_sched_barrier(0);
      }
      __builtin_amdgcn_s_barrier();
    }
  }

  // epilogue: C/D layout col=lane&15, row=(lane>>4)*4 + j (m89-verified)
  const int which = SPLIT3 ? (tn >> 12) : 0;
  const float* bp = SPLIT3 ? (which == 0 ? b0 : (which == 1 ? b1 : b2)) : b0;
  void* Cp = SPLIT3 ? (which == 0 ? C0 : (which == 1 ? C1 : C2)) : C0;
  const int tnn = SPLIT3 ? (tn & 4095) : tn;
  #pragma unroll
  for (int ni = 0; ni < 4; ++ni) {
    const int col = tnn + wn * 64 + ni * 16 + l16;
    const float bv = HAS_BIAS ? bp[col] : 0.f;
    #pragma unroll
    for (int mi = 0; mi < 8; ++mi) {
      #pragma unroll
      for (int jj = 0; jj < 4; ++jj) {
        const int row = tm + wm * 128 + mi * 16 + kg * 4 + jj;
        const float v = acc[mi][ni][jj] * alpha + bv;
        if (CF32) ((float*)Cp)[offC + (long)row * ldc + col] = v;
        else ((unsigned short*)Cp)[offC + (long)row * ldc + col] = f2bf(v);
      }
    }
  }
}

// ============================================================================
// f32 -> bf16 convert (vectorized, grid-stride), n8 = n/8
// ============================================================================
__global__ __launch_bounds__(256)
void cvt_bf16(const float* __restrict__ in, unsigned short* __restrict__ out, long n8)
{
  long i = (long)blockIdx.x * 256 + threadIdx.x;
  const long stride = (long)gridDim.x * 256;
  for (; i < n8; i += stride) {
    f32x4 v0 = *(const f32x4*)(in + i * 8);
    f32x4 v1 = *(const f32x4*)(in + i * 8 + 4);
    uint4v o;
    o[0] = cvt_pk_bf16(v0[0], v0[1]);
    o[1] = cvt_pk_bf16(v0[2], v0[3]);
    o[2] = cvt_pk_bf16(v1[0], v1[1]);
    o[3] = cvt_pk_bf16(v1[2], v1[3]);
    *(uint4v*)(out + i * 8) = o;
  }
}

// In-place LayerNorm over rows of 512 bf16. One wave/row. g,b f32.
__global__ __launch_bounds__(256)
void ln_rows(unsigned short* __restrict__ t, const float* __restrict__ g,
             const float* __restrict__ b)
{
  const int row = blockIdx.x * 4 + ((int)threadIdx.x >> 6);
  const int lane = (int)threadIdx.x & 63;
  unsigned short* p = t + (long)row * 512 + lane * 8;
  short8 rv = *(const short8*)p;
  float x[8];
  #pragma unroll
  for (int j = 0; j < 8; ++j) x[j] = bf2f((unsigned short)rv[j]);
  float s = 0.f;
  #pragma unroll
  for (int j = 0; j < 8; ++j) s += x[j];
  #pragma unroll
  for (int off = 32; off > 0; off >>= 1) s += __shfl_xor(s, off, 64);
  float mu = s * (1.f / 512.f);
  float vs = 0.f;
  #pragma unroll
  for (int j = 0; j < 8; ++j) { float d = x[j] - mu; vs += d * d; }
  #pragma unroll
  for (int off = 32; off > 0; off >>= 1) vs += __shfl_xor(vs, off, 64);
  float rs = rsqrtf(vs * (1.f / 512.f) + 1e-5f);
  f32x4 gv0 = *(const f32x4*)(g + lane * 8);
  f32x4 gv1 = *(const f32x4*)(g + lane * 8 + 4);
  f32x4 bv0 = *(const f32x4*)(b + lane * 8);
  f32x4 bv1 = *(const f32x4*)(b + lane * 8 + 4);
  short8 ov;
  #pragma unroll
  for (int j = 0; j < 4; ++j) ov[j] = (short)f2bf((x[j] - mu) * rs * gv0[j] + bv0[j]);
  #pragma unroll
  for (int j = 0; j < 4; ++j) ov[4 + j] = (short)f2bf((x[4 + j] - mu) * rs * gv1[j] + bv1[j]);
  *(short8*)p = ov;
}

// w = (val * gelu_exact(gate)) / max(||.||2, 1e-12); h rows are 1024 (val|gate)
__global__ __launch_bounds__(256)
void gate_norm(const unsigned short* __restrict__ h, unsigned short* __restrict__ w)
{
  const int row = blockIdx.x * 4 + ((int)threadIdx.x >> 6);
  const int lane = (int)threadIdx.x & 63;
  const unsigned short* hp = h + (long)row * 1024 + lane * 8;
  short8 vv = *(const short8*)hp;
  short8 gg = *(const short8*)(hp + 512);
  float wv[8];
  float ssq = 0.f;
  #pragma unroll
  for (int j = 0; j < 8; ++j) {
    float val = bf2f((unsigned short)vv[j]);
    float gt  = bf2f((unsigned short)gg[j]);
    float tt  = val * (0.5f * gt * (1.f + erff(gt * 0.70710678118654752f)));
    wv[j] = tt;
    ssq += tt * tt;
  }
  #pragma unroll
  for (int off = 32; off > 0; off >>= 1) ssq += __shfl_xor(ssq, off, 64);
  float scale = 1.f / fmaxf(sqrtf(ssq), 1e-12f);
  short8 ov;
  #pragma unroll
  for (int j = 0; j < 8; ++j) ov[j] = (short)f2bf(wv[j] * scale);
  *(short8*)(w + (long)row * 512 + lane * 8) = ov;
}

// v (B,S,E) bf16 -> vT (B*H, 512d, 512t)
__global__ __launch_bounds__(256)
void transpose_v(const unsigned short* __restrict__ v, unsigned short* __restrict__ vT)
{
  __shared__ alignas(16) unsigned short lt[64][72];
  const int bh = blockIdx.z;
  const int b = bh >> 3, hh = bh & 7;
  const int d0 = blockIdx.x * 64, t0 = blockIdx.y * 64;
  const int tid = (int)threadIdx.x;
  const unsigned short* src = v + (long)b * (512L * 4096L) + hh * 512;
  #pragma unroll
  for (int it = 0; it < 2; ++it) {
    int ci = it * 256 + tid;
    int r = ci >> 3, c8 = (ci & 7) * 8;
    *(short8*)&lt[r][c8] = *(const short8*)(src + (long)(t0 + r) * 4096 + d0 + c8);
  }
  __syncthreads();
  unsigned short* dst = vT + ((long)bh * 512 + d0) * 512 + t0;
  #pragma unroll
  for (int it = 0; it < 2; ++it) {
    int ci = it * 256 + tid;
    int rr = ci >> 3, c8 = (ci & 7) * 8;
    short8 o;
    #pragma unroll
    for (int j = 0; j < 8; ++j) o[j] = (short)lt[c8 + j][rr];
    *(short8*)(dst + (long)rr * 512 + c8) = o;
  }
}

extern "C" void kernel_launch(void* const* d_in, const int* in_sizes, int n_in,
                              void* d_out, int out_size, void* d_ws, size_t ws_size,
                              hipStream_t stream)
{
  (void)in_sizes; (void)n_in; (void)out_size; (void)ws_size;
  const float* x   = (const float*)d_in[0];
  const float* Wq  = (const float*)d_in[1];
  const float* bq  = (const float*)d_in[2];
  const float* Wk  = (const float*)d_in[3];
  const float* bk  = (const float*)d_in[4];
  const float* Wv  = (const float*)d_in[5];
  const float* bv  = (const float*)d_in[6];
  const float* g_q = (const float*)d_in[7];
  const float* b_q = (const float*)d_in[8];
  const float* g_k = (const float*)d_in[9];
  const float* b_k = (const float*)d_in[10];
  const float* Wg  = (const float*)d_in[11];
  const float* bg  = (const float*)d_in[12];
  const float* Wo  = (const float*)d_in[13];
  const float* bo  = (const float*)d_in[14];
  float* out = (float*)d_out;

  const long NE  = 33554432L;   // B*S*E
  const long NE2 = NE / 2;      // 4096*4096
  unsigned short* ws    = (unsigned short*)d_ws;
  // Layout (shorts), total 5.5*NE (369MB):
  unsigned short* xb    = ws;                    // NE
  unsigned short* Wqkv  = ws + NE;               // 1.5*NE (Wq|Wk|Wv rows)
  unsigned short* qbuf  = ws + NE + 3 * NE2;     // NE
  unsigned short* kbuf  = qbuf + NE;             // NE
  unsigned short* vbuf  = kbuf + NE;             // NE
  // Wqkv region reused after projections:
  unsigned short* Wgb   = Wqkv;                  // 1024x512
  unsigned short* Wob   = Wqkv + 524288;         // 4096x4096
  unsigned short* sbuf  = xb;                    // scores (x dead)
  unsigned short* vT    = qbuf;                  // q dead after scores
  unsigned short* hbuf  = kbuf;                  // spans kbuf+vbuf, both dead
  unsigned short* wbuf  = xb;                    // scores dead after h-GEMM
  unsigned short* obuf  = kbuf;                  // h dead after gate_norm

  dim3 blk256(256), blk512(512);
  const float isq = 0.044194173824159216f;  // 1/sqrt(512)

  cvt_bf16<<<16384, blk256, 0, stream>>>(x, xb, NE / 8);
  cvt_bf16<<<8192, blk256, 0, stream>>>(Wq, Wqkv, NE2 / 8);
  cvt_bf16<<<8192, blk256, 0, stream>>>(Wk, Wqkv + NE2, NE2 / 8);
  cvt_bf16<<<8192, blk256, 0, stream>>>(Wv, Wqkv + 2 * NE2, NE2 / 8);

  // merged q|k|v projection: (8192 x 12288) = xb @ Wqkv^T, split-3 epilogue
  gemm256<0, 1, 0, 1><<<1536, blk512, 0, stream>>>(
      xb, Wqkv, bq, bk, bv, qbuf, kbuf, vbuf,
      4096, 4096, 4096, 4096, 48, 1.f,
      0L, 0L, 1, 0L, 0L, 1, 0L, 0L, 1);

  // Wqkv dead -> convert Wg, Wo into its region
  cvt_bf16<<<256, blk256, 0, stream>>>(Wg, Wgb, 524288L / 8);
  cvt_bf16<<<8192, blk256, 0, stream>>>(Wo, Wob, NE2 / 8);

  ln_rows<<<16384, blk256, 0, stream>>>(qbuf, g_q, b_q);
  ln_rows<<<16384, blk256, 0, stream>>>(kbuf, g_k, b_k);

  // scores = q @ k^T / sqrt(HD), per (b,h) -> sbuf (=xb)
  gemm256<1, 0, 0, 0><<<dim3(4, 1, 128), blk512, 0, stream>>>(
      qbuf, kbuf, nullptr, nullptr, nullptr, sbuf, nullptr, nullptr,
      512, 4096, 4096, 512, 2, isq,
      2097152L, 512L, 8,
      2097152L, 512L, 8,
      262144L, 0L, 1);

  transpose_v<<<dim3(8, 8, 128), blk256, 0, stream>>>(vbuf, vT);

  // h = scores @ Wg^T + bg -> hbuf (=kbuf..vbuf)
  gemm256<1, 0, 0, 1><<<dim3(8, 1, 128), blk512, 0, stream>>>(
      sbuf, Wgb, bg, nullptr, nullptr, hbuf, nullptr, nullptr,
      512, 512, 512, 1024, 4, 1.f,
      262144L, 0L, 1,
      0L, 0L, 1,
      524288L, 0L, 1);

  gate_norm<<<16384, blk256, 0, stream>>>(hbuf, wbuf);

  // attn_out = w @ vT^T -> obuf, (B,S,E) layout
  gemm256<1, 0, 0, 0><<<dim3(4, 1, 128), blk512, 0, stream>>>(
      wbuf, vT, nullptr, nullptr, nullptr, obuf, nullptr, nullptr,
      512, 512, 512, 4096, 2, 1.f,
      262144L, 0L, 1,
      262144L, 0L, 1,
      2097152L, 512L, 8);

  // final = attn_out @ Wo^T + bo -> d_out (f32)
  gemm256<0, 0, 1, 1><<<512, blk512, 0, stream>>>(
      obuf, Wob, bo, nullptr, nullptr, out, nullptr, nullptr,
      4096, 4096, 4096, 4096, 16, 1.f,
      0L, 0L, 1, 0L, 0L, 1, 0L, 0L, 1);
}

// Round 7
// 1338.454 us; speedup vs baseline: 2.1222x; 1.0672x over previous
//
#include <hip/hip_runtime.h>
#include <math.h>

typedef __bf16 bf16x8 __attribute__((ext_vector_type(8)));
typedef float f32x4 __attribute__((ext_vector_type(4)));
typedef short short8 __attribute__((ext_vector_type(8)));
typedef unsigned int uint4v __attribute__((ext_vector_type(4)));

__device__ __forceinline__ float bf2f(unsigned short u) {
  union { unsigned int i; float f; } v; v.i = ((unsigned int)u) << 16; return v.f;
}
__device__ __forceinline__ unsigned short f2bf(float f) {
  union { float fl; unsigned int i; } v; v.fl = f;
  unsigned int x = v.i;
  return (unsigned short)((x + 0x7FFFu + ((x >> 16) & 1u)) >> 16);  // RNE
}
__device__ __forceinline__ unsigned int cvt_pk_bf16(float lo, float hi) {
  unsigned int r;
  asm("v_cvt_pk_bf16_f32 %0, %1, %2" : "=v"(r) : "v"(lo), "v"(hi));
  return r;
}
// async global->LDS, 16B per lane. lds ptr wave-uniform (HW adds lane*16).
__device__ __forceinline__ void gl_lds16(const unsigned short* g, void* l) {
  __builtin_amdgcn_global_load_lds(
      (const __attribute__((address_space(1))) unsigned int*)g,
      (__attribute__((address_space(3))) unsigned int*)l, 16, 0, 0);
}

// ============================================================================
// 256x256 bf16 GEMM, 16x16x32 MFMA, 4-phase K-tile schedule (0 bank conflicts,
// counted vmcnt). R7: even 2-load staging per phase, lgkmcnt(8) hoist on the
// 12-read phase, LDS-transpose coalesced bf16 epilogue.
//  BATCH=0: 1D grid, XCD-chunked + 4x4 super-tiled mapping. BATCH=1: batched.
//  SPLIT3: N spans 3 concatenated 4096-col groups (bias/output per tn>>12).
// ============================================================================
template<int BATCH, int SPLIT3, int CF32, int HAS_BIAS>
__global__ __launch_bounds__(512)
void gemm256(const unsigned short* __restrict__ A,
             const unsigned short* __restrict__ B,
             const float* __restrict__ b0, const float* __restrict__ b1,
             const float* __restrict__ b2,
             void* __restrict__ C0, void* __restrict__ C1, void* __restrict__ C2,
             int K, int lda, int ldb, int ldc, int nbn, float alpha,
             long sAo, long sAi, int nAi,
             long sBo, long sBi, int nBi,
             long sCo, long sCi, int nCi)
{
  __shared__ alignas(16) unsigned char LDS[131072];
  const int NT = K >> 6;   // even, >= 2

  int tm, tn;
  long offA = 0, offB = 0, offC = 0;
  if (BATCH) {
    const int bx = (int)blockIdx.x;
    tm = (bx / nbn) * 256;
    tn = (bx % nbn) * 256;
    const int z = (int)blockIdx.z;
    offA = (long)(z / nAi) * sAo + (long)(z % nAi) * sAi;
    offB = (long)(z / nBi) * sBo + (long)(z % nBi) * sBi;
    offC = (long)(z / nCi) * sCo + (long)(z % nCi) * sCi;
  } else {
    const int nwg = (int)gridDim.x;
    const int bid = (int)blockIdx.x;
    const int s = (bid & 7) * (nwg >> 3) + (bid >> 3);
    const int sTile = s >> 4, w = s & 15;
    const int snb = nbn >> 2;
    tm = ((sTile / snb) * 4 + (w >> 2)) * 256;
    tn = ((sTile % snb) * 4 + (w & 3)) * 256;
  }

  const int tid = (int)threadIdx.x;
  const int lane = tid & 63;
  const int wv = tid >> 6;      // 0..7
  const int wm = wv >> 2;       // 0..1 (A half)
  const int wn = wv & 3;        // 0..3
  const int l16 = lane & 15;
  const int kg = lane >> 4;

  // staging: linear LDS dest; content[o] = logical[o ^ ((row&7)<<4)], row=o>>7
  const int srow = tid >> 3;
  const int scolb = ((tid & 7) * 16) ^ (((tid >> 3) & 7) << 4);
  const unsigned short* Abase = A + offA + (long)tm * lda + (scolb >> 1);
  const unsigned short* Bbase = B + offB + (long)tn * ldb + (scolb >> 1);
  const int ldsw = wv * 1024;

  // frag read cols (full-XOR swizzle on byte col, row&7 == l16&7)
  const int colswz0 = (kg * 16) ^ ((l16 & 7) << 4);
  const int colswz1 = (64 + kg * 16) ^ ((l16 & 7) << 4);

  f32x4 acc[8][4];
  #pragma unroll
  for (int i = 0; i < 8; ++i)
    #pragma unroll
    for (int j = 0; j < 4; ++j)
      #pragma unroll
      for (int e = 0; e < 4; ++e) acc[i][j][e] = 0.f;

  auto stageAh = [&](int t, int h) {       // one A half-tile (2 loads)
    const int buf = t & 1;
    #pragma unroll
    for (int i = 0; i < 2; ++i)
      gl_lds16(Abase + (long)(h * 128 + srow + i * 64) * lda + t * 64,
               &LDS[buf * 32768 + h * 16384 + i * 8192 + ldsw]);
  };
  auto stageBh = [&](int t, int h) {       // one B half-tile (2 loads)
    const int buf = t & 1;
    #pragma unroll
    for (int i = 0; i < 2; ++i)
      gl_lds16(Bbase + (long)(h * 128 + srow + i * 64) * ldb + t * 64,
               &LDS[65536 + buf * 32768 + h * 16384 + i * 8192 + ldsw]);
  };

  // prologue: tiles 0,1 staged (8 loads each); wait tile 0 only
  stageAh(0, 0); stageAh(0, 1); stageBh(0, 0); stageBh(0, 1);
  stageAh(1, 0); stageAh(1, 1); stageBh(1, 0); stageBh(1, 1);
  asm volatile("s_waitcnt vmcnt(8)" ::: "memory");
  __builtin_amdgcn_s_barrier();

  // Staging ledger per tile t: j0 A(t+1)h0, j1 A(t+1)h1, j2 B(t+2)h0,
  // j3 B(t+2)h1. FIFO at tile-end vmcnt: B(t+1)[4] A(t+1)[4] | B(t+2)[4]
  // -> vmcnt(4) keeps B(t+2) in flight. Region safety: B(t) fully read at
  // j0 (j0-end barrier precedes j2 staging); A(buf^1) readers drained at
  // previous tile-end barrier (precedes j0/j1 staging).
  for (int t = 0; t < NT; ++t) {
    const unsigned char* aB = &LDS[(t & 1) * 32768 + wm * 16384];
    const unsigned char* bB = &LDS[65536 + (t & 1) * 32768 + (wn >> 1) * 16384];
    const int brow = (wn & 1) * 64;
    bf16x8 bfrag[4][2];
    #pragma unroll
    for (int j = 0; j < 4; ++j) {
      // ds-load this quadrant's A rows
      bf16x8 a0k0 = *(const bf16x8*)(aB + ((2 * j + 0) * 16 + l16) * 128 + colswz0);
      bf16x8 a0k1 = *(const bf16x8*)(aB + ((2 * j + 0) * 16 + l16) * 128 + colswz1);
      bf16x8 a1k0 = *(const bf16x8*)(aB + ((2 * j + 1) * 16 + l16) * 128 + colswz0);
      bf16x8 a1k1 = *(const bf16x8*)(aB + ((2 * j + 1) * 16 + l16) * 128 + colswz1);
      if (j == 0) {
        #pragma unroll
        for (int ni = 0; ni < 4; ++ni) {
          bfrag[ni][0] = *(const bf16x8*)(bB + (brow + ni * 16 + l16) * 128 + colswz0);
          bfrag[ni][1] = *(const bf16x8*)(bB + (brow + ni * 16 + l16) * 128 + colswz1);
        }
        if (t > 0 && t + 1 < NT) stageAh(t + 1, 0);
        asm volatile("s_waitcnt lgkmcnt(8)" ::: "memory");   // hoist: drain 4 oldest
      } else if (j == 1) {
        if (t > 0 && t + 1 < NT) stageAh(t + 1, 1);
      } else if (j == 2) {
        if (t + 2 < NT) stageBh(t + 2, 0);
      } else {
        if (t + 2 < NT) stageBh(t + 2, 1);
      }
      __builtin_amdgcn_s_barrier();
      asm volatile("s_waitcnt lgkmcnt(0)" ::: "memory");
      __builtin_amdgcn_sched_barrier(0);
      __builtin_amdgcn_s_setprio(1);
      #pragma unroll
      for (int ni = 0; ni < 4; ++ni) {
        acc[2 * j + 0][ni] = __builtin_amdgcn_mfma_f32_16x16x32_bf16(a0k0, bfrag[ni][0], acc[2 * j + 0][ni], 0, 0, 0);
        acc[2 * j + 0][ni] = __builtin_amdgcn_mfma_f32_16x16x32_bf16(a0k1, bfrag[ni][1], acc[2 * j + 0][ni], 0, 0, 0);
        acc[2 * j + 1][ni] = __builtin_amdgcn_mfma_f32_16x16x32_bf16(a1k0, bfrag[ni][0], acc[2 * j + 1][ni], 0, 0, 0);
        acc[2 * j + 1][ni] = __builtin_amdgcn_mfma_f32_16x16x32_bf16(a1k1, bfrag[ni][1], acc[2 * j + 1][ni], 0, 0, 0);
      }
      __builtin_amdgcn_s_setprio(0);
      if (j == 3) {
        if (t >= NT - 2) { asm volatile("s_waitcnt vmcnt(0)" ::: "memory"); }
        else             { asm volatile("s_waitcnt vmcnt(4)" ::: "memory"); }
        __builtin_amdgcn_sched_barrier(0);
      }
      __builtin_amdgcn_s_barrier();
    }
  }
  // last tile-end barrier passed: all waves' ds_reads drained -> LDS reusable

  // epilogue
  const int which = SPLIT3 ? (tn >> 12) : 0;
  const float* bp = SPLIT3 ? (which == 0 ? b0 : (which == 1 ? b1 : b2)) : b0;
  void* Cp = SPLIT3 ? (which == 0 ? C0 : (which == 1 ? C1 : C2)) : C0;
  const int tnn = SPLIT3 ? (tn & 4095) : tn;

  if (CF32) {
    // f32 path (final GEMM only): direct scattered stores
    #pragma unroll
    for (int ni = 0; ni < 4; ++ni) {
      const int col = tnn + wn * 64 + ni * 16 + l16;
      const float bv = HAS_BIAS ? bp[col] : 0.f;
      #pragma unroll
      for (int mi = 0; mi < 8; ++mi)
        #pragma unroll
        for (int jj = 0; jj < 4; ++jj) {
          const int row = tm + wm * 128 + mi * 16 + kg * 4 + jj;
          ((float*)Cp)[offC + (long)row * ldc + col] = acc[mi][ni][jj] * alpha + bv;
        }
    }
  } else {
    // bf16 path: per-wave LDS transpose -> fully coalesced 128B row segments
    unsigned short* lw = (unsigned short*)&LDS[wv * 16384];  // private 16KB
    #pragma unroll
    for (int ni = 0; ni < 4; ++ni) {
      const float bv = HAS_BIAS ? bp[tnn + wn * 64 + ni * 16 + l16] : 0.f;
      #pragma unroll
      for (int mi = 0; mi < 8; ++mi)
        #pragma unroll
        for (int jj = 0; jj < 4; ++jj)
          lw[(mi * 16 + kg * 4 + jj) * 64 + ni * 16 + l16] =
              f2bf(acc[mi][ni][jj] * alpha + bv);
    }
    asm volatile("s_waitcnt lgkmcnt(0)" ::: "memory");
    __builtin_amdgcn_sched_barrier(0);
    unsigned short* Cg = (unsigned short*)Cp + offC +
                         (long)(tm + wm * 128) * ldc + tnn + wn * 64;
    const int rr = lane >> 3, cc = (lane & 7) * 8;
    #pragma unroll
    for (int i = 0; i < 16; ++i) {
      short8 val = *(const short8*)&lw[(i * 8 + rr) * 64 + cc];
      *(short8*)(Cg + (long)(i * 8 + rr) * ldc + cc) = val;
    }
  }
}

// ============================================================================
// f32 -> bf16 convert (vectorized, grid-stride), n8 = n/8
// ============================================================================
__global__ __launch_bounds__(256)
void cvt_bf16(const float* __restrict__ in, unsigned short* __restrict__ out, long n8)
{
  long i = (long)blockIdx.x * 256 + threadIdx.x;
  const long stride = (long)gridDim.x * 256;
  for (; i < n8; i += stride) {
    f32x4 v0 = *(const f32x4*)(in + i * 8);
    f32x4 v1 = *(const f32x4*)(in + i * 8 + 4);
    uint4v o;
    o[0] = cvt_pk_bf16(v0[0], v0[1]);
    o[1] = cvt_pk_bf16(v0[2], v0[3]);
    o[2] = cvt_pk_bf16(v1[0], v1[1]);
    o[3] = cvt_pk_bf16(v1[2], v1[3]);
    *(uint4v*)(out + i * 8) = o;
  }
}

// In-place LayerNorm over rows of 512 bf16. One wave/row. g,b f32.
__global__ __launch_bounds__(256)
void ln_rows(unsigned short* __restrict__ t, const float* __restrict__ g,
             const float* __restrict__ b)
{
  const int row = blockIdx.x * 4 + ((int)threadIdx.x >> 6);
  const int lane = (int)threadIdx.x & 63;
  unsigned short* p = t + (long)row * 512 + lane * 8;
  short8 rv = *(const short8*)p;
  float x[8];
  #pragma unroll
  for (int j = 0; j < 8; ++j) x[j] = bf2f((unsigned short)rv[j]);
  float s = 0.f;
  #pragma unroll
  for (int j = 0; j < 8; ++j) s += x[j];
  #pragma unroll
  for (int off = 32; off > 0; off >>= 1) s += __shfl_xor(s, off, 64);
  float mu = s * (1.f / 512.f);
  float vs = 0.f;
  #pragma unroll
  for (int j = 0; j < 8; ++j) { float d = x[j] - mu; vs += d * d; }
  #pragma unroll
  for (int off = 32; off > 0; off >>= 1) vs += __shfl_xor(vs, off, 64);
  float rs = rsqrtf(vs * (1.f / 512.f) + 1e-5f);
  f32x4 gv0 = *(const f32x4*)(g + lane * 8);
  f32x4 gv1 = *(const f32x4*)(g + lane * 8 + 4);
  f32x4 bv0 = *(const f32x4*)(b + lane * 8);
  f32x4 bv1 = *(const f32x4*)(b + lane * 8 + 4);
  short8 ov;
  #pragma unroll
  for (int j = 0; j < 4; ++j) ov[j] = (short)f2bf((x[j] - mu) * rs * gv0[j] + bv0[j]);
  #pragma unroll
  for (int j = 0; j < 4; ++j) ov[4 + j] = (short)f2bf((x[4 + j] - mu) * rs * gv1[j] + bv1[j]);
  *(short8*)p = ov;
}

// w = (val * gelu_exact(gate)) / max(||.||2, 1e-12); h rows are 1024 (val|gate)
__global__ __launch_bounds__(256)
void gate_norm(const unsigned short* __restrict__ h, unsigned short* __restrict__ w)
{
  const int row = blockIdx.x * 4 + ((int)threadIdx.x >> 6);
  const int lane = (int)threadIdx.x & 63;
  const unsigned short* hp = h + (long)row * 1024 + lane * 8;
  short8 vv = *(const short8*)hp;
  short8 gg = *(const short8*)(hp + 512);
  float wv[8];
  float ssq = 0.f;
  #pragma unroll
  for (int j = 0; j < 8; ++j) {
    float val = bf2f((unsigned short)vv[j]);
    float gt  = bf2f((unsigned short)gg[j]);
    float tt  = val * (0.5f * gt * (1.f + erff(gt * 0.70710678118654752f)));
    wv[j] = tt;
    ssq += tt * tt;
  }
  #pragma unroll
  for (int off = 32; off > 0; off >>= 1) ssq += __shfl_xor(ssq, off, 64);
  float scale = 1.f / fmaxf(sqrtf(ssq), 1e-12f);
  short8 ov;
  #pragma unroll
  for (int j = 0; j < 8; ++j) ov[j] = (short)f2bf(wv[j] * scale);
  *(short8*)(w + (long)row * 512 + lane * 8) = ov;
}

// v (B,S,E) bf16 -> vT (B*H, 512d, 512t)
__global__ __launch_bounds__(256)
void transpose_v(const unsigned short* __restrict__ v, unsigned short* __restrict__ vT)
{
  __shared__ alignas(16) unsigned short lt[64][72];
  const int bh = blockIdx.z;
  const int b = bh >> 3, hh = bh & 7;
  const int d0 = blockIdx.x * 64, t0 = blockIdx.y * 64;
  const int tid = (int)threadIdx.x;
  const unsigned short* src = v + (long)b * (512L * 4096L) + hh * 512;
  #pragma unroll
  for (int it = 0; it < 2; ++it) {
    int ci = it * 256 + tid;
    int r = ci >> 3, c8 = (ci & 7) * 8;
    *(short8*)&lt[r][c8] = *(const short8*)(src + (long)(t0 + r) * 4096 + d0 + c8);
  }
  __syncthreads();
  unsigned short* dst = vT + ((long)bh * 512 + d0) * 512 + t0;
  #pragma unroll
  for (int it = 0; it < 2; ++it) {
    int ci = it * 256 + tid;
    int rr = ci >> 3, c8 = (ci & 7) * 8;
    short8 o;
    #pragma unroll
    for (int j = 0; j < 8; ++j) o[j] = (short)lt[c8 + j][rr];
    *(short8*)(dst + (long)rr * 512 + c8) = o;
  }
}

extern "C" void kernel_launch(void* const* d_in, const int* in_sizes, int n_in,
                              void* d_out, int out_size, void* d_ws, size_t ws_size,
                              hipStream_t stream)
{
  (void)in_sizes; (void)n_in; (void)out_size; (void)ws_size;
  const float* x   = (const float*)d_in[0];
  const float* Wq  = (const float*)d_in[1];
  const float* bq  = (const float*)d_in[2];
  const float* Wk  = (const float*)d_in[3];
  const float* bk  = (const float*)d_in[4];
  const float* Wv  = (const float*)d_in[5];
  const float* bv  = (const float*)d_in[6];
  const float* g_q = (const float*)d_in[7];
  const float* b_q = (const float*)d_in[8];
  const float* g_k = (const float*)d_in[9];
  const float* b_k = (const float*)d_in[10];
  const float* Wg  = (const float*)d_in[11];
  const float* bg  = (const float*)d_in[12];
  const float* Wo  = (const float*)d_in[13];
  const float* bo  = (const float*)d_in[14];
  float* out = (float*)d_out;

  const long NE  = 33554432L;   // B*S*E
  const long NE2 = NE / 2;      // 4096*4096
  unsigned short* ws    = (unsigned short*)d_ws;
  unsigned short* xb    = ws;                    // NE
  unsigned short* Wqkv  = ws + NE;               // 1.5*NE (Wq|Wk|Wv rows)
  unsigned short* qbuf  = ws + NE + 3 * NE2;     // NE
  unsigned short* kbuf  = qbuf + NE;             // NE
  unsigned short* vbuf  = kbuf + NE;             // NE
  unsigned short* Wgb   = Wqkv;                  // 1024x512 (after proj)
  unsigned short* Wob   = Wqkv + 524288;         // 4096x4096 (after proj)
  unsigned short* sbuf  = xb;                    // scores (x dead)
  unsigned short* vT    = qbuf;                  // q dead after scores
  unsigned short* hbuf  = kbuf;                  // spans kbuf+vbuf, both dead
  unsigned short* wbuf  = xb;                    // scores dead after h-GEMM
  unsigned short* obuf  = kbuf;                  // h dead after gate_norm

  dim3 blk256(256), blk512(512);
  const float isq = 0.044194173824159216f;  // 1/sqrt(512)

  cvt_bf16<<<16384, blk256, 0, stream>>>(x, xb, NE / 8);
  cvt_bf16<<<8192, blk256, 0, stream>>>(Wq, Wqkv, NE2 / 8);
  cvt_bf16<<<8192, blk256, 0, stream>>>(Wk, Wqkv + NE2, NE2 / 8);
  cvt_bf16<<<8192, blk256, 0, stream>>>(Wv, Wqkv + 2 * NE2, NE2 / 8);

  // merged q|k|v projection: (8192 x 12288) = xb @ Wqkv^T, split-3 epilogue
  gemm256<0, 1, 0, 1><<<1536, blk512, 0, stream>>>(
      xb, Wqkv, bq, bk, bv, qbuf, kbuf, vbuf,
      4096, 4096, 4096, 4096, 48, 1.f,
      0L, 0L, 1, 0L, 0L, 1, 0L, 0L, 1);

  // Wqkv dead -> convert Wg, Wo into its region
  cvt_bf16<<<256, blk256, 0, stream>>>(Wg, Wgb, 524288L / 8);
  cvt_bf16<<<8192, blk256, 0, stream>>>(Wo, Wob, NE2 / 8);

  ln_rows<<<16384, blk256, 0, stream>>>(qbuf, g_q, b_q);
  ln_rows<<<16384, blk256, 0, stream>>>(kbuf, g_k, b_k);

  // scores = q @ k^T / sqrt(HD), per (b,h) -> sbuf (=xb)
  gemm256<1, 0, 0, 0><<<dim3(4, 1, 128), blk512, 0, stream>>>(
      qbuf, kbuf, nullptr, nullptr, nullptr, sbuf, nullptr, nullptr,
      512, 4096, 4096, 512, 2, isq,
      2097152L, 512L, 8,
      2097152L, 512L, 8,
      262144L, 0L, 1);

  transpose_v<<<dim3(8, 8, 128), blk256, 0, stream>>>(vbuf, vT);

  // h = scores @ Wg^T + bg -> hbuf (=kbuf..vbuf)
  gemm256<1, 0, 0, 1><<<dim3(8, 1, 128), blk512, 0, stream>>>(
      sbuf, Wgb, bg, nullptr, nullptr, hbuf, nullptr, nullptr,
      512, 512, 512, 1024, 4, 1.f,
      262144L, 0L, 1,
      0L, 0L, 1,
      524288L, 0L, 1);

  gate_norm<<<16384, blk256, 0, stream>>>(hbuf, wbuf);

  // attn_out = w @ vT^T -> obuf, (B,S,E) layout
  gemm256<1, 0, 0, 0><<<dim3(4, 1, 128), blk512, 0, stream>>>(
      wbuf, vT, nullptr, nullptr, nullptr, obuf, nullptr, nullptr,
      512, 512, 512, 4096, 2, 1.f,
      262144L, 0L, 1,
      262144L, 0L, 1,
      2097152L, 512L, 8);

  // final = attn_out @ Wo^T + bo -> d_out (f32)
  gemm256<0, 0, 1, 1><<<512, blk512, 0, stream>>>(
      obuf, Wob, bo, nullptr, nullptr, out, nullptr, nullptr,
      4096, 4096, 4096, 4096, 16, 1.f,
      0L, 0L, 1, 0L, 0L, 1, 0L, 0L, 1);
}